// Round 2
// baseline (1500.685 us; speedup 1.0000x reference)
//
#include <hip/hip_runtime.h>

#define DTC 0.01f
#define LAM  2.88539008178f     // 2/ln2
#define L2E  1.44269504089f     // 1/ln2

typedef __attribute__((ext_vector_type(8))) short short8;
typedef __attribute__((ext_vector_type(4))) float floatx4;

#if __has_builtin(__builtin_amdgcn_exp2f)
#define EXP2F(x) __builtin_amdgcn_exp2f(x)
#else
#define EXP2F(x) exp2f(x)
#endif
#if __has_builtin(__builtin_amdgcn_rcpf)
#define RCPF(x) __builtin_amdgcn_rcpf(x)
#else
#define RCPF(x) (1.0f / (x))
#endif

__device__ __forceinline__ unsigned short f2bf(float f) {
    unsigned u = __float_as_uint(f);
    u += 0x7FFFu + ((u >> 16) & 1u);
    return (unsigned short)(u >> 16);
}
// 1/(1+2^y): with gate pre-activations pre-scaled by -1/ln2 this IS sigmoid;
// with +2/ln2 scaling, tanh = 1 - 2*rcp1p.
__device__ __forceinline__ float rcp1p(float y) {
    return RCPF(1.0f + EXP2F(y));
}
// Raw barrier: drains LDS ops for cross-wave visibility but NOT vmcnt, so
// wave0's out/res global stores stay in flight across barriers.
__device__ __forceinline__ void wg_barrier() {
    asm volatile("s_waitcnt lgkmcnt(0)" ::: "memory");
    __builtin_amdgcn_s_barrier();
}

#define U1S 136   // bf16 elements; byte stride 272 = 16*17 -> spread b128 reads
#define ES  68    // exchange buffer col stride (floats); 68*4B spreads quads

#define MFMA(a, b, c) __builtin_amdgcn_mfma_f32_16x16x32_bf16((a), (b), (c), 0, 0, 0)

// 8 waves: pair g = wave>>1 owns hidden cols [16g,16g+16); within the pair,
// p = wave&1 computes gates {2p, 2p+1} by MFMA, pre-activations are exchanged
// through E[4][16][ES] (fp32), and each wave runs the cell nonlinearity for
// rows [8p, 8p+8) only (2 elements/thread). Halves per-wave registers (no
// spill) and per-wave transcendental work; 2 waves/SIMD hide latency.
__global__ __launch_bounds__(512, 1) void lstm_mfma(
    const float* __restrict__ x,    const float* __restrict__ s0,
    const float* __restrict__ W_ih0,const float* __restrict__ W_hh0,
    const float* __restrict__ b_ih0,const float* __restrict__ b_hh0,
    const float* __restrict__ W_ih1,const float* __restrict__ W_hh1,
    const float* __restrict__ b_ih1,const float* __restrict__ b_hh1,
    const float* __restrict__ fc_W, const float* __restrict__ fc_b,
    const int* __restrict__ nsp,    float* __restrict__ out, int B)
{
    // U1: [16 rows m][cols: 0..63 = h_a(t) bf16, 64..127 = h_b(t) bf16]
    __shared__ __align__(16) unsigned short U1[16 * U1S];
    __shared__ float E[4 * 16 * ES];   // gate pre-activation exchange

    const int ns   = nsp[0];
    const int tid  = threadIdx.x;
    const int lane = tid & 63;
    const int wave = tid >> 6;        // 0..7
    const int il   = lane & 15;
    const int quad = lane >> 4;
    const int g    = wave >> 1;
    const int p    = wave & 1;
    const int col  = 16 * g + il;     // hidden column this pair owns
    const int bb   = blockIdx.x * 16;

    float* cal = out + (size_t)B * ns * 8;
    float* res = cal + ns;

    if (blockIdx.x == 0)
        for (int t = tid; t < ns; t += 512) cal[t] = t * DTC;

    for (int i = tid; i < 16 * U1S; i += 512) U1[i] = 0;

    // ---- constants: this wave's 2 gates (j = 2p+jl), cols n = 64j + col ----
    // Gate pre-scale folded into bf16 weights: gamma = -1/ln2 (sigmoid gates),
    // +2/ln2 (tanh gate g). Cell state carried LAM-scaled.
    // s removed from the MFMA path: gs[jl] carries gamma*(b0 + W_x*x + W_s*s(t))
    // in fp32, updated each step by MFMA(h_b(t-1), gamma*DT*(W_s@fc_W)) + gd.
    short8 B0[2][2], B1[2][4], M2f[2][2], BF[2];
    floatx4 gs[2];
    float gd[2], b1s[2];

    for (int jl = 0; jl < 2; ++jl) {
        const int j = 2 * p + jl;
        const float gam = (j == 2) ? LAM : -L2E;
        const int n = 64 * j + col;
        float ws[8];
        #pragma unroll
        for (int pp = 0; pp < 8; ++pp) ws[pp] = W_ih0[n * 16 + 8 + pp];

        #pragma unroll
        for (int kk = 0; kk < 2; ++kk) {        // G0: K = h_a(64)
            short8 f;
            #pragma unroll
            for (int jj = 0; jj < 8; ++jj) {
                int k = 32 * kk + 8 * quad + jj;
                f[jj] = (short)f2bf(gam * W_hh0[n * 64 + k]);
            }
            B0[jl][kk] = f;
        }
        #pragma unroll
        for (int kk = 0; kk < 4; ++kk) {        // G1: K = [h_a(64) | h_b(64)]
            short8 f;
            #pragma unroll
            for (int jj = 0; jj < 8; ++jj) {
                int k = 32 * kk + 8 * quad + jj;
                float w = (k < 64) ? W_ih1[n * 64 + k] : W_hh1[n * 64 + (k - 64)];
                f[jj] = (short)f2bf(gam * w);
            }
            B1[jl][kk] = f;
        }
        #pragma unroll
        for (int kk = 0; kk < 2; ++kk) {        // M2 = W_s @ fc_W
            short8 f;
            #pragma unroll
            for (int jj = 0; jj < 8; ++jj) {
                int k = 32 * kk + 8 * quad + jj;
                float acc = 0.0f;
                #pragma unroll
                for (int pp = 0; pp < 8; ++pp) acc += ws[pp] * fc_W[pp * 64 + k];
                f[jj] = (short)f2bf(gam * DTC * acc);
            }
            M2f[jl][kk] = f;
        }
        float accb = 0.0f;
        #pragma unroll
        for (int pp = 0; pp < 8; ++pp) accb += ws[pp] * fc_b[pp];
        gd[jl] = gam * DTC * accb;

        float bcol = b_ih0[n] + b_hh0[n];
        floatx4 gv;
        #pragma unroll
        for (int reg = 0; reg < 4; ++reg) {
            int m = 4 * quad + reg;
            float acc = bcol;
            #pragma unroll
            for (int k = 0; k < 8; ++k) acc += x[(bb + m) * 8 + k] * W_ih0[n * 16 + k];
            #pragma unroll
            for (int pp = 0; pp < 8; ++pp) acc += ws[pp] * s0[(bb + m) * 8 + pp];
            gv[reg] = gam * acc - gd[jl];   // t=0 update adds gd back
        }
        gs[jl] = gv;
        b1s[jl] = gam * (b_ih1[n] + b_hh1[n]);
    }
    #pragma unroll
    for (int kk = 0; kk < 2; ++kk) {            // FC head (wave0 uses it)
        short8 f;
        #pragma unroll
        for (int jj = 0; jj < 8; ++jj) {
            int k = 32 * kk + 8 * quad + jj;
            float w = (il < 8) ? fc_W[il * 64 + k] : 0.0f;
            f[jj] = (short)f2bf(w);
        }
        BF[kk] = f;
    }
    const float fcb = (il < 8) ? fc_b[il] : 0.0f;

    // ---- state ----
    float cA[2] = {0, 0}, cB[2] = {0, 0};       // LAM-scaled, rows 8p+2quad+{0,1}
    float s_reg[4];
    #pragma unroll
    for (int reg = 0; reg < 4; ++reg)
        s_reg[reg] = (il < 8) ? s0[(bb + 4 * quad + reg) * 8 + il] : 0.0f;

    short8 a10 = {0,0,0,0,0,0,0,0};             // h_a(t-1) carried in registers
    short8 a11 = {0,0,0,0,0,0,0,0};
    floatx4 p1[2];

    // LDS base pointers (loop-invariant)
    const unsigned short* Ar = &U1[il * U1S + 8 * quad];        // A-frag reads
    unsigned short* Hw = &U1[(8 * p + 2 * quad) * U1S + col];   // h writes
    float* Ew = &E[(32 * p + 4 * quad) * ES + col];             // preact writes
    const float* Er = &E[(8 * p + 2 * quad) * ES + col];        // preact reads

    wg_barrier();

    // Barriers per step: X (preact0 exchange), B (h_a ready), Y (preact1
    // exchange), C (h_b ready). All E/U1 read-before-write hazards are
    // separated by one of these; a-frags are carried in registers.
    #pragma unroll 1
    for (int t = 0; t < ns; ++t) {
        // ---- phase 1: gates of cell0 + partials ----
        short8 a12 = *(const short8*)(Ar + 64);   // h_b(t-1)
        short8 a13 = *(const short8*)(Ar + 96);

        #pragma unroll
        for (int jl = 0; jl < 2; ++jl) {
            floatx4 z = gs[jl];                   // affine s-path update
            z = MFMA(a12, M2f[jl][0], z);
            z = MFMA(a13, M2f[jl][1], z);
            #pragma unroll
            for (int r = 0; r < 4; ++r) z[r] += gd[jl];
            gs[jl] = z;
            floatx4 q = z;                        // preact0 = gs(t) + B0*h_a(t-1)
            q = MFMA(a10, B0[jl][0], q);
            q = MFMA(a11, B0[jl][1], q);
            #pragma unroll
            for (int r = 0; r < 4; ++r)
                Ew[jl * (16 * ES) + r * ES] = q[r];
            floatx4 pz = {b1s[jl], b1s[jl], b1s[jl], b1s[jl]};
            pz = MFMA(a13, B1[jl][3], pz);        // layer-1 h_b partial
            pz = MFMA(a12, B1[jl][2], pz);
            p1[jl] = pz;
        }
        wg_barrier();   // X

        // ---- cell 0 (rows 8p+2quad+e) ----
        #pragma unroll
        for (int e = 0; e < 2; ++e) {
            float pi = Er[e * ES + 0 * (16 * ES)];
            float pf = Er[e * ES + 1 * (16 * ES)];
            float pg = Er[e * ES + 2 * (16 * ES)];
            float po = Er[e * ES + 3 * (16 * ES)];
            float iv = rcp1p(pi);
            float fv = rcp1p(pf);
            float gr = rcp1p(pg);
            float ov = rcp1p(po);
            float gl = __builtin_fmaf(gr, -2.0f * LAM, LAM);   // LAM*tanh(g)
            float c  = __builtin_fmaf(fv, cA[e], iv * gl);
            cA[e]    = c;
            float r2 = rcp1p(c);
            float h  = __builtin_fmaf(-2.0f, ov * r2, ov);
            Hw[e * U1S] = f2bf(h);                // h_a(t)
        }
        wg_barrier();   // B

        // ---- phase 2: gates of cell1 ----
        a10 = *(const short8*)(Ar + 0);           // h_a(t), reused next iter
        a11 = *(const short8*)(Ar + 32);

        if (t && wave == 0) {                     // deferred FC(t-1)
            floatx4 so = {fcb, fcb, fcb, fcb};
            so = MFMA(a12, BF[0], so);
            so = MFMA(a13, BF[1], so);
            #pragma unroll
            for (int reg = 0; reg < 4; ++reg) {
                s_reg[reg] += so[reg] * DTC;
                if (il < 8) {
                    size_t o = ((size_t)(bb + 4 * quad + reg) * ns + (t - 1)) * 8 + il;
                    out[o] = s_reg[reg];
                    res[o] = so[reg];
                }
            }
        }

        #pragma unroll
        for (int jl = 0; jl < 2; ++jl) {
            floatx4 z = p1[jl];
            z = MFMA(a10, B1[jl][0], z);
            z = MFMA(a11, B1[jl][1], z);
            #pragma unroll
            for (int r = 0; r < 4; ++r)
                Ew[jl * (16 * ES) + r * ES] = z[r];
        }
        wg_barrier();   // Y

        // ---- cell 1 ----
        #pragma unroll
        for (int e = 0; e < 2; ++e) {
            float pi = Er[e * ES + 0 * (16 * ES)];
            float pf = Er[e * ES + 1 * (16 * ES)];
            float pg = Er[e * ES + 2 * (16 * ES)];
            float po = Er[e * ES + 3 * (16 * ES)];
            float iv = rcp1p(pi);
            float fv = rcp1p(pf);
            float gr = rcp1p(pg);
            float ov = rcp1p(po);
            float gl = __builtin_fmaf(gr, -2.0f * LAM, LAM);
            float c  = __builtin_fmaf(fv, cB[e], iv * gl);
            cB[e]    = c;
            float r2 = rcp1p(c);
            float h  = __builtin_fmaf(-2.0f, ov * r2, ov);
            Hw[e * U1S + 64] = f2bf(h);           // h_b(t)
        }
        wg_barrier();   // C
    }

    // epilogue: deferred FC for the final step
    if (wave == 0) {
        short8 a12 = *(const short8*)(Ar + 64);
        short8 a13 = *(const short8*)(Ar + 96);
        floatx4 so = {fcb, fcb, fcb, fcb};
        so = MFMA(a12, BF[0], so);
        so = MFMA(a13, BF[1], so);
        #pragma unroll
        for (int reg = 0; reg < 4; ++reg) {
            s_reg[reg] += so[reg] * DTC;
            if (il < 8) {
                size_t o = ((size_t)(bb + 4 * quad + reg) * ns + (ns - 1)) * 8 + il;
                out[o] = s_reg[reg];
                res[o] = so[reg];
            }
        }
    }
}

extern "C" void kernel_launch(void* const* d_in, const int* in_sizes, int n_in,
                              void* d_out, int out_size, void* d_ws, size_t ws_size,
                              hipStream_t stream) {
    const float* x     = (const float*)d_in[0];
    const float* s0    = (const float*)d_in[1];
    const float* W_ih0 = (const float*)d_in[2];
    const float* W_hh0 = (const float*)d_in[3];
    const float* b_ih0 = (const float*)d_in[4];
    const float* b_hh0 = (const float*)d_in[5];
    const float* W_ih1 = (const float*)d_in[6];
    const float* W_hh1 = (const float*)d_in[7];
    const float* b_ih1 = (const float*)d_in[8];
    const float* b_hh1 = (const float*)d_in[9];
    const float* fc_W  = (const float*)d_in[10];
    const float* fc_b  = (const float*)d_in[11];
    const int*   nsp   = (const int*)d_in[12];
    (void)d_ws; (void)ws_size; (void)n_in; (void)out_size;
    int B = in_sizes[0] / 8;          // 4096
    dim3 grid(B / 16), block(512);    // 256 blocks -> 1 per CU, 8 waves
    hipLaunchKernelGGL(lstm_mfma, grid, block, 0, stream,
        x, s0, W_ih0, W_hh0, b_ih0, b_hh0, W_ih1, W_hh1, b_ih1, b_hh1,
        fc_W, fc_b, nsp, (float*)d_out, B);
}